// Round 9
// baseline (788.174 us; speedup 1.0000x reference)
//
#include <hip/hip_runtime.h>
#include <hip/hip_bf16.h>

// ---------------------------------------------------------------------------
// 2-layer GATConv (heads=1). N=50000, E=800000, Cin=128, Ch=256, Co=128, Ed=8.
// 7-dispatch pipeline:
//   memset | pre_fat(hist+ea-sums ∥ W-split) | scanfill(scan+barrier+CSR-fill)
//   | gemm1 | agg1 | gemm2 | agg2
// CSR-by-dst + single-pass flash softmax-aggregation, 2-term bf16 MFMA GEMMs
// (A bf16, W hi+lo), fused attention row-dots in GEMM epilogue.
// ---------------------------------------------------------------------------

#define NEG_SLOPE 0.2f
#define EHB 1024           // ea_hist blocks inside pre_fat

typedef unsigned short u16;
typedef short short8 __attribute__((ext_vector_type(8)));
typedef float v4f __attribute__((ext_vector_type(4)));
typedef u16 u16x4 __attribute__((ext_vector_type(4)));
typedef u16 u16x8 __attribute__((ext_vector_type(8)));

__device__ __forceinline__ u16 f2bf(float f) {
    unsigned u = __float_as_uint(f);
    return (u16)((u + 0x7fffu + ((u >> 16) & 1u)) >> 16);
}
__device__ __forceinline__ float bf2f(u16 h) {
    return __uint_as_float(((unsigned)h) << 16);
}
__device__ __forceinline__ float bf_lo(int v) { return __uint_as_float(((unsigned)v) << 16); }
__device__ __forceinline__ float bf_hi(int v) { return __uint_as_float(((unsigned)v) & 0xffff0000u); }
__device__ __forceinline__ float lrelu(float x) {
    return x >= 0.f ? x : NEG_SLOPE * x;
}
__device__ __forceinline__ int ld_acq(int* p) {
    return __hip_atomic_load(p, __ATOMIC_ACQUIRE, __HIP_MEMORY_SCOPE_AGENT);
}
__device__ __forceinline__ void st_rel(int* p, int v) {
    __hip_atomic_store(p, v, __ATOMIC_RELEASE, __HIP_MEMORY_SCOPE_AGENT);
}
__device__ __forceinline__ float ld_f_agent(const float* p) {
    return __hip_atomic_load(p, __ATOMIC_RELAXED, __HIP_MEMORY_SCOPE_AGENT);
}

// ---- pre_fat: [0..EHB): dst histogram + edge_attr column sums (streaming)
//               [EHB..EHB+256): W1^T / W2^T bf16 hi/lo splits
__global__ __launch_bounds__(256) void pre_fat_kernel(
        const float* __restrict__ ea, const int* __restrict__ dst,
        float* __restrict__ mean_acc, int* __restrict__ deg, int E,
        const float* __restrict__ W1, u16* __restrict__ w1thi, u16* __restrict__ w1tlo,
        const float* __restrict__ W2, u16* __restrict__ w2thi, u16* __restrict__ w2tlo) {
    int tid = threadIdx.x;
    if (blockIdx.x >= EHB) {
        int t = (blockIdx.x - EHB) * 256 + tid;
        if (t < 128 * 256) {               // W1 [Cin=128][Ch=256]
            int k = t >> 8, m = t & 255;
            float v = W1[t];
            u16 h = f2bf(v);
            w1thi[(size_t)m * 128 + k] = h;
            w1tlo[(size_t)m * 128 + k] = f2bf(v - bf2f(h));
        } else {                           // W2 [Ch=256][Co=128]
            t -= 128 * 256;
            int k = t >> 7, m = t & 127;
            float v = W2[t];
            u16 h = f2bf(v);
            w2thi[(size_t)m * 256 + k] = h;
            w2tlo[(size_t)m * 256 + k] = f2bf(v - bf2f(h));
        }
        return;
    }
    __shared__ float red[8];
    if (tid < 8) red[tid] = 0.f;
    __syncthreads();
    float s[8] = {0.f};
    int stride = EHB * 256;
    for (int e = blockIdx.x * 256 + tid; e < E; e += stride) {
        atomicAdd(&deg[dst[e]], 1);
        const float4 v0 = *(const float4*)&ea[(size_t)e * 8];
        const float4 v1 = *(const float4*)&ea[(size_t)e * 8 + 4];
        s[0] += v0.x; s[1] += v0.y; s[2] += v0.z; s[3] += v0.w;
        s[4] += v1.x; s[5] += v1.y; s[6] += v1.z; s[7] += v1.w;
    }
#pragma unroll
    for (int j = 0; j < 8; ++j) atomicAdd(&red[j], s[j]);
    __syncthreads();
    if (tid < 8) atomicAdd(&mean_acc[tid], red[tid]);
}

// ---- scanfill: blocks [0..SCB) scan deg -> row_start/cursor (co-resident
// barrier; last arriver also computes we_vec + ae_loop); ALL blocks then fill
// the CSR: one packed 16B store per edge {src, ae1, ae2, 0}, a_e computed
// inline from ea @ we_vec. Grid = ceil(E/256) blocks.
__global__ __launch_bounds__(256) void scanfill_kernel(
        const int* __restrict__ deg, int* __restrict__ row_start,
        int* __restrict__ cursor, int* __restrict__ partials, int* __restrict__ pprefix,
        int* __restrict__ gcount, int* __restrict__ gflag1,
        int* __restrict__ gdone, int* __restrict__ gflag2,
        int N, int n, int SCB,
        const float* __restrict__ mean_acc, float Einv,
        const float* __restrict__ We1, const float* __restrict__ ae1v,
        const float* __restrict__ We2, const float* __restrict__ ae2v,
        float* __restrict__ we_vec_g, float* __restrict__ ae_loop,
        const int* __restrict__ src, const int* __restrict__ dst,
        const float* __restrict__ ea, float4* __restrict__ epack, int E) {
    __shared__ int s[256];
    __shared__ float wv[16];
    __shared__ int amLast, bpre_sh;
    int t = threadIdx.x, bid = blockIdx.x;
    if (t < 16) wv[t] = 0.f;

    if (bid < SCB) {
        int i = bid * 256 + t;
        int v = (i < N) ? deg[i] : 0;
        s[t] = v; __syncthreads();
        for (int off = 1; off < 256; off <<= 1) {
            int u = (t >= off) ? s[t - off] : 0;
            __syncthreads();
            s[t] += u;
            __syncthreads();
        }
        int incl = s[t];
        if (t == 0) {
            partials[bid] = s[255];
            __threadfence();
            int c = __hip_atomic_fetch_add(gcount, 1, __ATOMIC_ACQ_REL, __HIP_MEMORY_SCOPE_AGENT);
            amLast = (c == SCB - 1);
        }
        __syncthreads();
        if (amLast) {
            int pv = (t < SCB) ? ld_acq(&partials[t]) : 0;
            __syncthreads();
            s[t] = pv; __syncthreads();
            for (int off = 1; off < 256; off <<= 1) {
                int u = (t >= off) ? s[t - off] : 0;
                __syncthreads();
                s[t] += u;
                __syncthreads();
            }
            if (t < SCB) pprefix[t] = s[t] - pv;
            // we_vec: wv[j] = sum_k We1[j][k]*ae1v[k]; wv[8+j] for We2
            {
                int lane = t & 63;
                float a1 = ae1v[t];              // Ch == 256 == blockDim
#pragma unroll
                for (int j = 0; j < 8; ++j) {
                    float v2 = We1[j * 256 + t] * a1;
#pragma unroll
                    for (int o = 32; o; o >>= 1) v2 += __shfl_down(v2, o);
                    if (lane == 0) atomicAdd(&wv[j], v2);
                }
                if (t < 128) {
                    float a2 = ae2v[t];          // Co == 128
#pragma unroll
                    for (int j = 0; j < 8; ++j) {
                        float v2 = We2[j * 128 + t] * a2;
#pragma unroll
                        for (int o = 32; o; o >>= 1) v2 += __shfl_down(v2, o);
                        if (lane == 0) atomicAdd(&wv[8 + j], v2);
                    }
                }
            }
            __syncthreads();
            if (t < 16) we_vec_g[t] = wv[t];
            if (t == 0) {
                float s1 = 0.f, s2 = 0.f;
#pragma unroll
                for (int j = 0; j < 8; ++j) {
                    float m = mean_acc[j] * Einv;
                    s1 += m * wv[j];
                    s2 += m * wv[8 + j];
                }
                ae_loop[0] = s1; ae_loop[1] = s2;
            }
            __threadfence();
            __syncthreads();
            if (t == 0) st_rel(gflag1, 1);
        }
        if (t == 0) {
            while (ld_acq(gflag1) == 0) __builtin_amdgcn_s_sleep(2);
            bpre_sh = ld_acq(&pprefix[bid]);
        }
        __syncthreads();
        int ex = bpre_sh + incl - v;
        if (i < n) row_start[i] = ex;
        if (i < N) cursor[i] = ex;
        __threadfence();
        __syncthreads();
        if (t == 0) {
            int c2 = __hip_atomic_fetch_add(gdone, 1, __ATOMIC_ACQ_REL, __HIP_MEMORY_SCOPE_AGENT);
            if (c2 == SCB - 1) st_rel(gflag2, 1);
        }
    }
    // ---- fill phase (all blocks) ----
    if (t == 0) {
        while (ld_acq(gflag2) == 0) __builtin_amdgcn_s_sleep(2);
    }
    __syncthreads();
    if (t < 16) wv[t] = ld_f_agent(&we_vec_g[t]);
    __syncthreads();
    int e = bid * 256 + t;
    if (e < E) {
        int d = dst[e];
        int idx = atomicAdd(&cursor[d], 1);
        const float4 v0 = *(const float4*)&ea[(size_t)e * 8];
        const float4 v1 = *(const float4*)&ea[(size_t)e * 8 + 4];
        float s1 = v0.x * wv[0] + v0.y * wv[1] + v0.z * wv[2] + v0.w * wv[3]
                 + v1.x * wv[4] + v1.y * wv[5] + v1.z * wv[6] + v1.w * wv[7];
        float s2 = v0.x * wv[8] + v0.y * wv[9] + v0.z * wv[10] + v0.w * wv[11]
                 + v1.x * wv[12] + v1.y * wv[13] + v1.z * wv[14] + v1.w * wv[15];
        epack[idx] = make_float4(__int_as_float(src[e]), s1, s2, 0.f);
    }
}

// ---- gemm1: 2-term bf16 MFMA, A = fp32 (converted during staging) ----------
#define BK 32
#define LDA 40   // 32 + 8 pad (u16)
__global__ __launch_bounds__(256) void gemm1_mfma_kernel(
        const float* __restrict__ A32,
        const u16* __restrict__ Bh_g, const u16* __restrict__ Bl_g,
        u16* __restrict__ Cb, int Nrows, int K, int M,
        const float* __restrict__ av, const float* __restrict__ bv,
        float* __restrict__ as_out, float* __restrict__ ad_out) {
    __shared__ u16 Ah[128 * LDA], Bh[128 * LDA], Bl[128 * LDA];
    int tid = threadIdx.x;
    int lane = tid & 63;
    int wv = tid >> 6;
    int wm = wv >> 1, wn = wv & 1;
    int l15 = lane & 15, quad = lane >> 4;
    int rb = blockIdx.y * 128;
    int cb = blockIdx.x * 128;

    v4f acc[4][4];
#pragma unroll
    for (int mi = 0; mi < 4; ++mi)
#pragma unroll
        for (int ni = 0; ni < 4; ++ni) acc[mi][ni] = (v4f){0.f, 0.f, 0.f, 0.f};

    int sr = tid >> 1;
    int sc = (tid & 1) * 16;

    for (int kc = 0; kc < K; kc += BK) {
        int gr = rb + sr;
        u16x8 a0 = {0,0,0,0,0,0,0,0}, a1 = {0,0,0,0,0,0,0,0};
        if (gr < Nrows) {
            const float* pa = A32 + (size_t)gr * K + kc + sc;
            float4 f0 = *(const float4*)pa;
            float4 f1 = *(const float4*)(pa + 4);
            float4 f2 = *(const float4*)(pa + 8);
            float4 f3 = *(const float4*)(pa + 12);
            a0 = (u16x8){f2bf(f0.x), f2bf(f0.y), f2bf(f0.z), f2bf(f0.w),
                         f2bf(f1.x), f2bf(f1.y), f2bf(f1.z), f2bf(f1.w)};
            a1 = (u16x8){f2bf(f2.x), f2bf(f2.y), f2bf(f2.z), f2bf(f2.w),
                         f2bf(f3.x), f2bf(f3.y), f2bf(f3.z), f2bf(f3.w)};
        }
        size_t bb = (size_t)(cb + sr) * K + kc + sc;
        u16x8 b0 = *(const u16x8*)(Bh_g + bb);
        u16x8 b1 = *(const u16x8*)(Bh_g + bb + 8);
        u16x8 b2 = *(const u16x8*)(Bl_g + bb);
        u16x8 b3 = *(const u16x8*)(Bl_g + bb + 8);
        *(u16x8*)&Ah[sr * LDA + sc] = a0;
        *(u16x8*)&Ah[sr * LDA + sc + 8] = a1;
        *(u16x8*)&Bh[sr * LDA + sc] = b0;
        *(u16x8*)&Bh[sr * LDA + sc + 8] = b1;
        *(u16x8*)&Bl[sr * LDA + sc] = b2;
        *(u16x8*)&Bl[sr * LDA + sc + 8] = b3;
        __syncthreads();
        short8 ah[4], bh[4], bl[4];
#pragma unroll
        for (int mi = 0; mi < 4; ++mi)
            ah[mi] = *(const short8*)&Ah[(wm * 64 + mi * 16 + l15) * LDA + quad * 8];
#pragma unroll
        for (int ni = 0; ni < 4; ++ni) {
            int r = (wn * 64 + ni * 16 + l15) * LDA + quad * 8;
            bh[ni] = *(const short8*)&Bh[r];
            bl[ni] = *(const short8*)&Bl[r];
        }
#pragma unroll
        for (int mi = 0; mi < 4; ++mi)
#pragma unroll
            for (int ni = 0; ni < 4; ++ni) {
                acc[mi][ni] = __builtin_amdgcn_mfma_f32_16x16x32_bf16(ah[mi], bh[ni], acc[mi][ni], 0, 0, 0);
                acc[mi][ni] = __builtin_amdgcn_mfma_f32_16x16x32_bf16(ah[mi], bl[ni], acc[mi][ni], 0, 0, 0);
            }
        __syncthreads();
    }
#pragma unroll
    for (int mi = 0; mi < 4; ++mi)
#pragma unroll
        for (int ni = 0; ni < 4; ++ni)
#pragma unroll
            for (int reg = 0; reg < 4; ++reg) {
                int row = rb + wm * 64 + mi * 16 + quad * 4 + reg;
                if (row < Nrows)
                    Cb[(size_t)row * M + cb + wn * 64 + ni * 16 + l15] = f2bf(acc[mi][ni][reg]);
            }
    float sd[4][4] = {}, dd[4][4] = {};
#pragma unroll
    for (int ni = 0; ni < 4; ++ni) {
        int col = cb + wn * 64 + ni * 16 + l15;
        float a = av[col], b = bv[col];
#pragma unroll
        for (int mi = 0; mi < 4; ++mi)
#pragma unroll
            for (int reg = 0; reg < 4; ++reg) {
                sd[mi][reg] += acc[mi][ni][reg] * a;
                dd[mi][reg] += acc[mi][ni][reg] * b;
            }
    }
#pragma unroll
    for (int off = 1; off < 16; off <<= 1)
#pragma unroll
        for (int mi = 0; mi < 4; ++mi)
#pragma unroll
            for (int reg = 0; reg < 4; ++reg) {
                sd[mi][reg] += __shfl_xor(sd[mi][reg], off);
                dd[mi][reg] += __shfl_xor(dd[mi][reg], off);
            }
    if (l15 == 0)
#pragma unroll
        for (int mi = 0; mi < 4; ++mi) {
            int row0 = rb + wm * 64 + mi * 16 + quad * 4;
#pragma unroll
            for (int reg = 0; reg < 4; ++reg)
                if (row0 + reg < Nrows) {
                    atomicAdd(as_out + row0 + reg, sd[mi][reg]);
                    atomicAdd(ad_out + row0 + reg, dd[mi][reg]);
                }
        }
}

// ---- gemm2: same structure, A already bf16 ---------------------------------
__global__ __launch_bounds__(256) void gemm_mfma_kernel(
        const u16* __restrict__ A_g,
        const u16* __restrict__ Bh_g, const u16* __restrict__ Bl_g,
        u16* __restrict__ Cb, int Nrows, int K, int M,
        const float* __restrict__ av, const float* __restrict__ bv,
        float* __restrict__ as_out, float* __restrict__ ad_out) {
    __shared__ u16 Ah[128 * LDA], Bh[128 * LDA], Bl[128 * LDA];
    int tid = threadIdx.x;
    int lane = tid & 63;
    int wv = tid >> 6;
    int wm = wv >> 1, wn = wv & 1;
    int l15 = lane & 15, quad = lane >> 4;
    int rb = blockIdx.y * 128;
    int cb = blockIdx.x * 128;

    v4f acc[4][4];
#pragma unroll
    for (int mi = 0; mi < 4; ++mi)
#pragma unroll
        for (int ni = 0; ni < 4; ++ni) acc[mi][ni] = (v4f){0.f, 0.f, 0.f, 0.f};

    int sr = tid >> 1;
    int sc = (tid & 1) * 16;

    for (int kc = 0; kc < K; kc += BK) {
        int gr = rb + sr;
        u16x8 a0 = {0,0,0,0,0,0,0,0}, a1 = {0,0,0,0,0,0,0,0};
        if (gr < Nrows) {
            size_t ba = (size_t)gr * K + kc + sc;
            a0 = *(const u16x8*)(A_g + ba);
            a1 = *(const u16x8*)(A_g + ba + 8);
        }
        size_t bb = (size_t)(cb + sr) * K + kc + sc;
        u16x8 b0 = *(const u16x8*)(Bh_g + bb);
        u16x8 b1 = *(const u16x8*)(Bh_g + bb + 8);
        u16x8 b2 = *(const u16x8*)(Bl_g + bb);
        u16x8 b3 = *(const u16x8*)(Bl_g + bb + 8);
        *(u16x8*)&Ah[sr * LDA + sc] = a0;
        *(u16x8*)&Ah[sr * LDA + sc + 8] = a1;
        *(u16x8*)&Bh[sr * LDA + sc] = b0;
        *(u16x8*)&Bh[sr * LDA + sc + 8] = b1;
        *(u16x8*)&Bl[sr * LDA + sc] = b2;
        *(u16x8*)&Bl[sr * LDA + sc + 8] = b3;
        __syncthreads();
        short8 ah[4], bh[4], bl[4];
#pragma unroll
        for (int mi = 0; mi < 4; ++mi)
            ah[mi] = *(const short8*)&Ah[(wm * 64 + mi * 16 + l15) * LDA + quad * 8];
#pragma unroll
        for (int ni = 0; ni < 4; ++ni) {
            int r = (wn * 64 + ni * 16 + l15) * LDA + quad * 8;
            bh[ni] = *(const short8*)&Bh[r];
            bl[ni] = *(const short8*)&Bl[r];
        }
#pragma unroll
        for (int mi = 0; mi < 4; ++mi)
#pragma unroll
            for (int ni = 0; ni < 4; ++ni) {
                acc[mi][ni] = __builtin_amdgcn_mfma_f32_16x16x32_bf16(ah[mi], bh[ni], acc[mi][ni], 0, 0, 0);
                acc[mi][ni] = __builtin_amdgcn_mfma_f32_16x16x32_bf16(ah[mi], bl[ni], acc[mi][ni], 0, 0, 0);
            }
        __syncthreads();
    }
#pragma unroll
    for (int mi = 0; mi < 4; ++mi)
#pragma unroll
        for (int ni = 0; ni < 4; ++ni)
#pragma unroll
            for (int reg = 0; reg < 4; ++reg) {
                int row = rb + wm * 64 + mi * 16 + quad * 4 + reg;
                if (row < Nrows)
                    Cb[(size_t)row * M + cb + wn * 64 + ni * 16 + l15] = f2bf(acc[mi][ni][reg]);
            }
    float sd[4][4] = {}, dd[4][4] = {};
#pragma unroll
    for (int ni = 0; ni < 4; ++ni) {
        int col = cb + wn * 64 + ni * 16 + l15;
        float a = av[col], b = bv[col];
#pragma unroll
        for (int mi = 0; mi < 4; ++mi)
#pragma unroll
            for (int reg = 0; reg < 4; ++reg) {
                sd[mi][reg] += acc[mi][ni][reg] * a;
                dd[mi][reg] += acc[mi][ni][reg] * b;
            }
    }
#pragma unroll
    for (int off = 1; off < 16; off <<= 1)
#pragma unroll
        for (int mi = 0; mi < 4; ++mi)
#pragma unroll
            for (int reg = 0; reg < 4; ++reg) {
                sd[mi][reg] += __shfl_xor(sd[mi][reg], off);
                dd[mi][reg] += __shfl_xor(dd[mi][reg], off);
            }
    if (l15 == 0)
#pragma unroll
        for (int mi = 0; mi < 4; ++mi) {
            int row0 = rb + wm * 64 + mi * 16 + quad * 4;
#pragma unroll
            for (int reg = 0; reg < 4; ++reg)
                if (row0 + reg < Nrows) {
                    atomicAdd(as_out + row0 + reg, sd[mi][reg]);
                    atomicAdd(ad_out + row0 + reg, dd[mi][reg]);
                }
        }
}

// ---- single-pass FLASH softmax-aggregation, L1 (C=256), wave per node ------
__global__ __launch_bounds__(256) void agg1_kernel(const int* __restrict__ row_start,
                                                   const float4* __restrict__ epack,
                                                   const float* __restrict__ asv,
                                                   const float* __restrict__ adv,
                                                   const float* __restrict__ ae_loop,
                                                   const u16* __restrict__ Hb,
                                                   u16* __restrict__ ohi,
                                                   const float* __restrict__ bias, int N) {
    __shared__ float2 xch[4][64];
    int lane = threadIdx.x & 63;
    int wvi = threadIdx.x >> 6;
    int node = blockIdx.x * 4 + wvi;
    if (node >= N) return;
    int st = row_start[node], en = row_start[node + 1];
    float ad = adv[node];
    float aloop = lrelu(asv[node] + ad + ae_loop[0]);
    float m = aloop, sum = 1.f;
    float acc0, acc1, acc2, acc3;
    {
        int2 hv = *(const int2*)(Hb + (size_t)node * 256 + lane * 4);
        acc0 = bf_lo(hv.x); acc1 = bf_hi(hv.x);
        acc2 = bf_lo(hv.y); acc3 = bf_hi(hv.y);
    }
    for (int base = st; base < en; base += 64) {
        int i = base + lane;
        float al = -3.0e38f; int sreg = 0;
        if (i < en) {
            float4 ep = epack[i];
            sreg = __float_as_int(ep.x);
            al = lrelu(asv[sreg] + ad + ep.y);
        }
        float cm = al;
#pragma unroll
        for (int o = 1; o < 64; o <<= 1) cm = fmaxf(cm, __shfl_xor(cm, o));
        if (cm > m) {
            float sc = __expf(m - cm);
            acc0 *= sc; acc1 *= sc; acc2 *= sc; acc3 *= sc;
            sum *= sc; m = cm;
        }
        float w = (i < en) ? __expf(al - m) : 0.f;
        float wsum = w;
#pragma unroll
        for (int o = 1; o < 64; o <<= 1) wsum += __shfl_xor(wsum, o);
        sum += wsum;
        xch[wvi][lane] = make_float2(w, __int_as_float(sreg));
        int cnt = min(64, en - base);
        int j = 0;
        for (; j + 4 <= cnt; j += 4) {
            float2 e0 = xch[wvi][j], e1 = xch[wvi][j + 1];
            float2 e2 = xch[wvi][j + 2], e3 = xch[wvi][j + 3];
            int2 h0 = *(const int2*)(Hb + (size_t)__float_as_int(e0.y) * 256 + lane * 4);
            int2 h1 = *(const int2*)(Hb + (size_t)__float_as_int(e1.y) * 256 + lane * 4);
            int2 h2 = *(const int2*)(Hb + (size_t)__float_as_int(e2.y) * 256 + lane * 4);
            int2 h3 = *(const int2*)(Hb + (size_t)__float_as_int(e3.y) * 256 + lane * 4);
            acc0 += e0.x * bf_lo(h0.x) + e1.x * bf_lo(h1.x) + e2.x * bf_lo(h2.x) + e3.x * bf_lo(h3.x);
            acc1 += e0.x * bf_hi(h0.x) + e1.x * bf_hi(h1.x) + e2.x * bf_hi(h2.x) + e3.x * bf_hi(h3.x);
            acc2 += e0.x * bf_lo(h0.y) + e1.x * bf_lo(h1.y) + e2.x * bf_lo(h2.y) + e3.x * bf_lo(h3.y);
            acc3 += e0.x * bf_hi(h0.y) + e1.x * bf_hi(h1.y) + e2.x * bf_hi(h2.y) + e3.x * bf_hi(h3.y);
        }
        for (; j < cnt; ++j) {
            float2 e0 = xch[wvi][j];
            int2 h0 = *(const int2*)(Hb + (size_t)__float_as_int(e0.y) * 256 + lane * 4);
            acc0 += e0.x * bf_lo(h0.x); acc1 += e0.x * bf_hi(h0.x);
            acc2 += e0.x * bf_lo(h0.y); acc3 += e0.x * bf_hi(h0.y);
        }
    }
    float inv = 1.f / sum;
    const float4 bvv = *(const float4*)(bias + lane * 4);
    float t0 = acc0 * inv + bvv.x, t1 = acc1 * inv + bvv.y;
    float t2 = acc2 * inv + bvv.z, t3 = acc3 * inv + bvv.w;
    t0 = t0 > 0.f ? t0 : 0.f; t1 = t1 > 0.f ? t1 : 0.f;
    t2 = t2 > 0.f ? t2 : 0.f; t3 = t3 > 0.f ? t3 : 0.f;
    u16x4 h;
    h.x = f2bf(t0); h.y = f2bf(t1); h.z = f2bf(t2); h.w = f2bf(t3);
    *(u16x4*)(ohi + (size_t)node * 256 + lane * 4) = h;
}

// ---- single-pass FLASH softmax-aggregation, L2 (C=128) ---------------------
__global__ __launch_bounds__(256) void agg2_kernel(const int* __restrict__ row_start,
                                                   const float4* __restrict__ epack,
                                                   const float* __restrict__ asv,
                                                   const float* __restrict__ adv,
                                                   const float* __restrict__ ae_loop,
                                                   const u16* __restrict__ Hb,
                                                   float* __restrict__ out,
                                                   const float* __restrict__ bias, int N) {
    __shared__ float2 xch[4][64];
    int lane = threadIdx.x & 63;
    int wvi = threadIdx.x >> 6;
    int node = blockIdx.x * 4 + wvi;
    if (node >= N) return;
    int st = row_start[node], en = row_start[node + 1];
    float ad = adv[node];
    float aloop = lrelu(asv[node] + ad + ae_loop[1]);
    float m = aloop, sum = 1.f;
    float acc0, acc1;
    {
        int hv = *(const int*)(Hb + (size_t)node * 128 + lane * 2);
        acc0 = bf_lo(hv); acc1 = bf_hi(hv);
    }
    for (int base = st; base < en; base += 64) {
        int i = base + lane;
        float al = -3.0e38f; int sreg = 0;
        if (i < en) {
            float4 ep = epack[i];
            sreg = __float_as_int(ep.x);
            al = lrelu(asv[sreg] + ad + ep.z);
        }
        float cm = al;
#pragma unroll
        for (int o = 1; o < 64; o <<= 1) cm = fmaxf(cm, __shfl_xor(cm, o));
        if (cm > m) {
            float sc = __expf(m - cm);
            acc0 *= sc; acc1 *= sc;
            sum *= sc; m = cm;
        }
        float w = (i < en) ? __expf(al - m) : 0.f;
        float wsum = w;
#pragma unroll
        for (int o = 1; o < 64; o <<= 1) wsum += __shfl_xor(wsum, o);
        sum += wsum;
        xch[wvi][lane] = make_float2(w, __int_as_float(sreg));
        int cnt = min(64, en - base);
        int j = 0;
        for (; j + 4 <= cnt; j += 4) {
            float2 e0 = xch[wvi][j], e1 = xch[wvi][j + 1];
            float2 e2 = xch[wvi][j + 2], e3 = xch[wvi][j + 3];
            int h0 = *(const int*)(Hb + (size_t)__float_as_int(e0.y) * 128 + lane * 2);
            int h1 = *(const int*)(Hb + (size_t)__float_as_int(e1.y) * 128 + lane * 2);
            int h2 = *(const int*)(Hb + (size_t)__float_as_int(e2.y) * 128 + lane * 2);
            int h3 = *(const int*)(Hb + (size_t)__float_as_int(e3.y) * 128 + lane * 2);
            acc0 += e0.x * bf_lo(h0) + e1.x * bf_lo(h1) + e2.x * bf_lo(h2) + e3.x * bf_lo(h3);
            acc1 += e0.x * bf_hi(h0) + e1.x * bf_hi(h1) + e2.x * bf_hi(h2) + e3.x * bf_hi(h3);
        }
        for (; j < cnt; ++j) {
            float2 e0 = xch[wvi][j];
            int h0 = *(const int*)(Hb + (size_t)__float_as_int(e0.y) * 128 + lane * 2);
            acc0 += e0.x * bf_lo(h0); acc1 += e0.x * bf_hi(h0);
        }
    }
    float inv = 1.f / sum;
    size_t o = (size_t)node * 128 + lane * 2;
    out[o]     = acc0 * inv + bias[lane * 2];
    out[o + 1] = acc1 * inv + bias[lane * 2 + 1];
}

extern "C" void kernel_launch(void* const* d_in, const int* in_sizes, int n_in,
                              void* d_out, int out_size, void* d_ws, size_t ws_size,
                              hipStream_t stream) {
    const int Cin = 128, Ch = 256, Co = 128;
    const int N = in_sizes[0] / Cin;        // 50000
    const int E = in_sizes[1] / 2;          // 800000

    const float* x   = (const float*)d_in[0];
    const int*   src = (const int*)d_in[1];
    const int*   dst = src + E;
    const float* ea  = (const float*)d_in[2];
    const float* W1  = (const float*)d_in[3];
    const float* We1 = (const float*)d_in[4];
    const float* as1 = (const float*)d_in[5];
    const float* ad1 = (const float*)d_in[6];
    const float* ae1 = (const float*)d_in[7];
    const float* b1  = (const float*)d_in[8];
    const float* W2  = (const float*)d_in[9];
    const float* We2 = (const float*)d_in[10];
    const float* as2 = (const float*)d_in[11];
    const float* ad2 = (const float*)d_in[12];
    const float* ae2 = (const float*)d_in[13];
    const float* b2  = (const float*)d_in[14];
    float* out = (float*)d_out;

    // workspace layout (4-byte units)
    float* ws = (float*)d_ws;
    size_t off = 0;
    u16* h1b = (u16*)(ws + off); off += (size_t)N * Ch / 2;   // bf16 h (reused as h2b)
    u16* g1b = (u16*)(ws + off); off += (size_t)N * Ch / 2;   // agg1 output (gemm2 A)
    float4* epack = (float4*)(ws + off); off += (size_t)E * 4;  // packed CSR edges
    int* row_start = (int*)(ws + off); off += (size_t)N + 1;
    int* cursor    = (int*)(ws + off); off += (size_t)N;
    int* partials  = (int*)(ws + off); off += 256;
    int* pprefix   = (int*)(ws + off); off += 256;
    u16* w1thi = (u16*)(ws + off); off += (size_t)Cin * Ch / 2;
    u16* w1tlo = (u16*)(ws + off); off += (size_t)Cin * Ch / 2;
    u16* w2thi = (u16*)(ws + off); off += (size_t)Ch * Co / 2;
    u16* w2tlo = (u16*)(ws + off); off += (size_t)Ch * Co / 2;
    // contiguous zero-region: deg | asv1 adv1 asv2 adv2 | misc | sync
    int*   deg  = (int*)(ws + off); off += (size_t)N + 1;
    float* asv1 = ws + off; off += (size_t)N;
    float* adv1 = ws + off; off += (size_t)N;
    float* asv2 = ws + off; off += (size_t)N;
    float* adv2 = ws + off; off += (size_t)N;
    float* misc = ws + off; off += 32;
    float* mean_acc = misc;
    float* we_vec_g = misc + 8;     // 16 floats (layer1 | layer2)
    float* ae_loop  = misc + 24;
    int* gcount = (int*)(ws + off); off += 1;
    int* gflag1 = (int*)(ws + off); off += 1;
    int* gdone  = (int*)(ws + off); off += 1;
    int* gflag2 = (int*)(ws + off); off += 1;

    const int n1 = N + 1;
    const int SCB = (n1 + 255) / 256;     // 196 scan blocks (co-resident)
    const int FB  = (E + 255) / 256;      // 3125 fill blocks

    // one memset zeroes deg + 4 dot-buffers + misc + sync flags
    hipMemsetAsync(deg, 0, ((size_t)5 * N + 37) * sizeof(float), stream);

    // ---- pre_fat: hist + ea column sums (1024 blocks) || W splits (256) ----
    pre_fat_kernel<<<EHB + 256, 256, 0, stream>>>(
        ea, dst, mean_acc, deg, E, W1, w1thi, w1tlo, W2, w2thi, w2tlo);

    // ---- scanfill: scan + we_vec/ae_loop + barrier + CSR fill --------------
    scanfill_kernel<<<FB, 256, 0, stream>>>(
        deg, row_start, cursor, partials, pprefix, gcount, gflag1, gdone, gflag2,
        N, n1, SCB, mean_acc, 1.0f / (float)E,
        We1, ae1, We2, ae2, we_vec_g, ae_loop,
        src, dst, ea, epack, E);

    // ---- layer 1 ----------------------------------------------------------
    {
        dim3 grid(Ch / 128, (N + 127) / 128);
        gemm1_mfma_kernel<<<grid, 256, 0, stream>>>(x, w1thi, w1tlo, h1b, N, Cin, Ch,
                                                    as1, ad1, asv1, adv1);
    }
    agg1_kernel<<<(N + 3) / 4, 256, 0, stream>>>(row_start, epack, asv1, adv1, ae_loop,
                                                 h1b, g1b, b1, N);

    // ---- layer 2 ----------------------------------------------------------
    u16* h2b = h1b; // reuse (agg1 consumed h1b)
    {
        dim3 grid(Co / 128, (N + 127) / 128);
        gemm_mfma_kernel<<<grid, 256, 0, stream>>>(g1b, w2thi, w2tlo, h2b, N, Ch, Co,
                                                   as2, ad2, asv2, adv2);
    }
    agg2_kernel<<<(N + 3) / 4, 256, 0, stream>>>(row_start, epack, asv2, adv2, ae_loop,
                                                 h2b, out, b2, N);
}